// Round 1
// baseline (532.841 us; speedup 1.0000x reference)
//
#include <hip/hip_runtime.h>

#define V      6890
#define NJ     24
#define NB     10
#define NP     207
#define NK     19
#define NBATCH 2048
#define KP     224      // padded K: 10 beta + 207 lrotmin + 1 const + 6 zero
#define KC     217      // index of the constant-1 column (-> v_template)
#define VC     (V*3)    // 20670

#define BN   32         // n-tile
#define BV   64         // vertex tile
#define BVC  192        // BV*3
#define ASTR 232        // Asm LDS row stride (shorts), padded
#define BSTR 40         // Bsm LDS row stride (shorts), padded (16B-aligned rows)
#define VSTR 196        // vh/verts LDS row stride (floats)

using bh8   = __attribute__((ext_vector_type(8))) short;          // 8 x bf16
using u16x8 = __attribute__((ext_vector_type(8))) unsigned short;
using f32x4 = __attribute__((ext_vector_type(4))) float;

__constant__ int PAR[NJ] = {-1,0,0,0,1,2,3,4,5,6,7,8,9,9,9,12,13,14,16,17,18,19,20,21};

__device__ __forceinline__ unsigned short f2bf(float f) {
    unsigned int u = __float_as_uint(f);
    u += 0x7FFFu + ((u >> 16) & 1u);   // RNE; no NaNs in this data
    return (unsigned short)(u >> 16);
}

// ---------------- K1: JB[j, c, m] = J_regressor . [v_template | shapedirs] ----------------
// 792 outputs, one wave per output (dot over V).
__global__ __launch_bounds__(256) void k_jb(const float* __restrict__ Jreg,
                                            const float* __restrict__ vtmpl,
                                            const float* __restrict__ sdirs,
                                            float* __restrict__ JB) {
    int o = blockIdx.x * 4 + (threadIdx.x >> 6);
    int lane = threadIdx.x & 63;
    if (o >= NJ * 33) return;
    int j = o / 33, t = o % 33, c = t / 11, m = t % 11;
    const float* jr = Jreg + j * V;
    float s = 0.f;
    if (m == 0) {
        for (int v = lane; v < V; v += 64) s += jr[v] * vtmpl[v*3 + c];
    } else {
        for (int v = lane; v < V; v += 64) s += jr[v] * sdirs[(v*3 + c)*NB + (m-1)];
    }
    #pragma unroll
    for (int d = 1; d < 64; d <<= 1) s += __shfl_xor(s, d);
    if (lane == 0) JB[(j*3 + c)*11 + m] = s;
}

// ---------------- K3: Bmat[vc][k] (bf16) = [shapedirs | posedirs | v_template | 0] ----------------
__global__ __launch_bounds__(256) void k_bmat(const float* __restrict__ sdirs,
                                              const float* __restrict__ pdirs,
                                              const float* __restrict__ vtmpl,
                                              unsigned short* __restrict__ Bmat) {
    int gid = blockIdx.x * 256 + threadIdx.x;
    if (gid >= VC * KP) return;
    int vc = gid / KP, k = gid % KP;
    float val;
    if (k < NB)       val = sdirs[vc*NB + k];
    else if (k < KC)  val = pdirs[vc*NP + (k - NB)];
    else if (k == KC) val = vtmpl[vc];
    else              val = 0.0f;
    Bmat[gid] = f2bf(val);
}

// ---------------- K2: per-n rodrigues, J, kinematic chain, G_rel (+trans), A-row ----------------
__global__ __launch_bounds__(128) void k_pern(const float* __restrict__ beta,
                                              const float* __restrict__ theta,
                                              const float* __restrict__ trans,
                                              const float* __restrict__ JB,
                                              unsigned short* __restrict__ Arow,
                                              unsigned short* __restrict__ Gt) {
    int n = blockIdx.x, tid = threadIdx.x;
    __shared__ float Rsm[NJ][9];
    __shared__ float Jsm[NJ][3];
    __shared__ float Gsm[NJ][12];   // 3x4, e = a*4+b

    if (tid < NJ) {
        const float* th = theta + (n*NJ + tid)*3;
        float x = th[0], y = th[1], z = th[2];
        float nrm = sqrtf(x*x + y*y + z*z);
        float t = fmaxf(nrm, 1.1754944e-38f);
        float inv = 1.0f / t;
        float rx = x*inv, ry = y*inv, rz = z*inv;
        float c = cosf(t), s = sinf(t), oc = 1.0f - c;
        Rsm[tid][0] = c + oc*rx*rx;      Rsm[tid][1] = oc*rx*ry - s*rz;  Rsm[tid][2] = oc*rx*rz + s*ry;
        Rsm[tid][3] = oc*ry*rx + s*rz;   Rsm[tid][4] = c + oc*ry*ry;     Rsm[tid][5] = oc*ry*rz - s*rx;
        Rsm[tid][6] = oc*rz*rx - s*ry;   Rsm[tid][7] = oc*rz*ry + s*rx;  Rsm[tid][8] = c + oc*rz*rz;
    }
    if (tid < NJ*3) {
        int j = tid/3, c = tid%3;
        float s = JB[(j*3+c)*11 + 0];
        #pragma unroll
        for (int b = 0; b < NB; ++b) s += JB[(j*3+c)*11 + 1 + b] * beta[n*NB + b];
        Jsm[j][c] = s;
    }
    __syncthreads();

    if (tid < 12) {   // G[0] = A(R0, J0), top 3 rows
        int a = tid >> 2, b = tid & 3;
        Gsm[0][a*4+b] = (b < 3) ? Rsm[0][a*3+b] : Jsm[0][a];
    }
    __syncthreads();
    for (int i = 1; i < NJ; ++i) {
        if (tid < 12) {
            int a = tid >> 2, b = tid & 3;
            int p = PAR[i];
            float acc = (b == 3) ? Gsm[p][a*4+3] : 0.0f;
            #pragma unroll
            for (int k = 0; k < 3; ++k) {
                float aval = (b < 3) ? Rsm[i][k*3+b] : (Jsm[i][k] - Jsm[p][k]);
                acc += Gsm[p][a*4+k] * aval;
            }
            Gsm[i][a*4+b] = acc;
        }
        __syncthreads();
    }
    // G_rel translation column: t' = t - R_part.J_j + trans  (trans folds since sum_j w = 1)
    if (tid < NJ*3) {
        int j = tid/3, a = tid%3;
        float t3 = Gsm[j][a*4+3]
                 - (Gsm[j][a*4+0]*Jsm[j][0] + Gsm[j][a*4+1]*Jsm[j][1] + Gsm[j][a*4+2]*Jsm[j][2])
                 + trans[n*3 + a];
        Gsm[j][a*4+3] = t3;   // only this lane reads/writes col 3 of row (j,a)
    }
    __syncthreads();
    // Gt[n][e=0..15][j=0..31] bf16, zero-padded (MFMA B operand for LBS GEMM)
    unsigned short* gt = Gt + n*512;
    for (int idx = tid; idx < 512; idx += 128) {
        int e = idx >> 5, j = idx & 31;
        float val = (e < 12 && j < NJ) ? Gsm[j][e] : 0.0f;
        gt[idx] = f2bf(val);
    }
    // A-row: [beta(10) | lrotmin(207) | 1 | 0...]
    unsigned short* ar = Arow + n*KP;
    for (int k = tid; k < KP; k += 128) {
        float val;
        if (k < NB) val = beta[n*NB + k];
        else if (k < KC) {
            int p = k - NB; int jj = p/9 + 1; int rr = p%9;
            val = Rsm[jj][rr] - ((rr==0 || rr==4 || rr==8) ? 1.0f : 0.0f);
        } else if (k == KC) val = 1.0f;
        else val = 0.0f;
        ar[k] = f2bf(val);
    }
}

// ---------------- K4: fused pose GEMM (MFMA) + LBS GEMM (MFMA) + apply ----------------
__global__ __launch_bounds__(256, 2) void k_main(const unsigned short* __restrict__ Arow,
                                                 const unsigned short* __restrict__ Bmat,
                                                 const unsigned short* __restrict__ Gt,
                                                 const float* __restrict__ weights,
                                                 float* __restrict__ verts) {
    __shared__ __attribute__((aligned(16))) unsigned short Asm[BN][ASTR];
    __shared__ __attribute__((aligned(16))) unsigned short Bsm[2][BVC][BSTR];
    __shared__ __attribute__((aligned(16))) float vhsm[BN][VSTR];

    int tid = threadIdx.x;
    int wv = tid >> 6, lane = tid & 63;
    int nb = blockIdx.x, vb = blockIdx.y;      // x-fastest => B tile stays hot in L2
    int n0 = nb * BN, v0 = vb * BV, vc0 = v0 * 3;

    // stage A tile (32 contiguous rows of 224 bf16)
    {
        const u16x8* src = (const u16x8*)(Arow + n0*KP);
        for (int q = tid; q < BN*KP/8; q += 256) {     // 896
            u16x8 d = src[q];
            int r = q / (KP/8), k8 = q % (KP/8);
            *(u16x8*)&Asm[r][k8*8] = d;
        }
    }
    // W fragments: A-operand of LBS GEMM, rows=v, k=j (pad j>=24 with 0)
    bh8 wfrag[4];
    {
        int jg = lane >> 4, vrl = lane & 15;
        #pragma unroll
        for (int mt = 0; mt < 4; ++mt) {
            int vr = v0 + mt*16 + vrl;
            bh8 f = {0,0,0,0,0,0,0,0};
            if (jg < 3 && vr < V) {
                const float4* wp = (const float4*)(weights + vr*NJ + jg*8);
                float4 w0 = wp[0], w1 = wp[1];
                f[0]=(short)f2bf(w0.x); f[1]=(short)f2bf(w0.y); f[2]=(short)f2bf(w0.z); f[3]=(short)f2bf(w0.w);
                f[4]=(short)f2bf(w1.x); f[5]=(short)f2bf(w1.y); f[6]=(short)f2bf(w1.z); f[7]=(short)f2bf(w1.w);
            }
            wfrag[mt] = f;
        }
    }

    auto stageB = [&](int buf, int ks) {
        #pragma unroll
        for (int it = 0; it < 3; ++it) {
            int q = tid + it*256;                  // 768 chunks of 16B
            int row = q >> 2, part = q & 3;
            int vc = vc0 + row;
            u16x8 d = {0,0,0,0,0,0,0,0};
            if (vc < VC) d = *(const u16x8*)(Bmat + vc*KP + ks*32 + part*8);
            *(u16x8*)&Bsm[buf][row][part*8] = d;
        }
    };

    // GEMM1: vh[n, vc] = Arow . Bmat^T   (K=224, double-buffered)
    f32x4 acc[2][3] = {};
    stageB(0, 0);
    __syncthreads();
    for (int ks = 0; ks < KP/32; ++ks) {
        if (ks < KP/32 - 1) stageB((ks+1)&1, ks+1);
        int cur = ks & 1;
        bh8 af[2], bfr[3];
        #pragma unroll
        for (int mt = 0; mt < 2; ++mt)
            af[mt] = *(const bh8*)&Asm[mt*16 + (lane&15)][ks*32 + 8*(lane>>4)];
        #pragma unroll
        for (int ct = 0; ct < 3; ++ct)
            bfr[ct] = *(const bh8*)&Bsm[cur][wv*48 + ct*16 + (lane&15)][8*(lane>>4)];
        #pragma unroll
        for (int mt = 0; mt < 2; ++mt)
            #pragma unroll
            for (int ct = 0; ct < 3; ++ct)
                acc[mt][ct] = __builtin_amdgcn_mfma_f32_16x16x32_bf16(af[mt], bfr[ct], acc[mt][ct], 0, 0, 0);
        __syncthreads();
    }
    // spill vh tile to LDS (f32)
    #pragma unroll
    for (int mt = 0; mt < 2; ++mt)
        #pragma unroll
        for (int ct = 0; ct < 3; ++ct)
            #pragma unroll
            for (int r = 0; r < 4; ++r)
                vhsm[mt*16 + (lane>>4)*4 + r][wv*48 + ct*16 + (lane&15)] = acc[mt][ct][r];
    __syncthreads();

    // GEMM2 + apply: T[v,e] = W . G_rel^T, verts = T.[vh,1]; verts tile reuses Bsm LDS
    float* vertsm = (float*)&Bsm[0][0][0];     // [BN][VSTR] f32, 25088B <= 30720B
    int e = lane & 15, jg = lane >> 4;
    int b = e & 3, a = e >> 2;
    #pragma unroll 1
    for (int nl = 0; nl < 8; ++nl) {
        int n_loc = wv*8 + nl;
        int n_g = n0 + n_loc;
        bh8 gfrag = *(const bh8*)(Gt + n_g*512 + e*32 + jg*8);
        #pragma unroll
        for (int mt = 0; mt < 4; ++mt) {
            f32x4 z = {0.f, 0.f, 0.f, 0.f};
            f32x4 t = __builtin_amdgcn_mfma_f32_16x16x32_bf16(wfrag[mt], gfrag, z, 0, 0, 0);
            #pragma unroll
            for (int r = 0; r < 4; ++r) {
                int v_loc = mt*16 + jg*4 + r;
                float m = (b == 3) ? 1.0f : vhsm[n_loc][v_loc*3 + b];
                float p = t[r] * m;
                p += __shfl_xor(p, 1);
                p += __shfl_xor(p, 2);
                if (a < 3 && b == 0) vertsm[n_loc*VSTR + v_loc*3 + a] = p;
            }
        }
    }
    __syncthreads();
    // coalesced write-out (float2: rows are 8B-aligned, 20670 even)
    for (int q = tid; q < BN*(BVC/2); q += 256) {
        int r = q / (BVC/2), c2 = q % (BVC/2);
        int vc = vc0 + c2*2;
        if (vc < VC) {
            float2 d = *(float2*)&vertsm[r*VSTR + c2*2];
            *(float2*)(verts + (long long)(n0 + r)*VC + vc) = d;
        }
    }
}

// ---------------- K5: joints[n,k,c] = sum_v verts[n,v,c] * jreg[v,k] ----------------
__global__ __launch_bounds__(256) void k_joints(const float* __restrict__ verts,
                                                const float* __restrict__ jreg,
                                                float* __restrict__ joints) {
    int n = blockIdx.x, tid = threadIdx.x;
    float acc[NK*3];
    #pragma unroll
    for (int i = 0; i < NK*3; ++i) acc[i] = 0.f;
    const float* vr = verts + (long long)n*VC;
    for (int v = tid; v < V; v += 256) {
        float x = vr[v*3+0], y = vr[v*3+1], z = vr[v*3+2];
        const float* jw = jreg + v*NK;
        #pragma unroll
        for (int k = 0; k < NK; ++k) {
            float w = jw[k];
            acc[k*3+0] += w*x; acc[k*3+1] += w*y; acc[k*3+2] += w*z;
        }
    }
    __shared__ float red[4][NK*3];
    #pragma unroll
    for (int i = 0; i < NK*3; ++i) {
        float s = acc[i];
        #pragma unroll
        for (int d = 1; d < 64; d <<= 1) s += __shfl_xor(s, d);
        if ((tid & 63) == 0) red[tid >> 6][i] = s;
    }
    __syncthreads();
    if (tid < NK*3)
        joints[n*NK*3 + tid] = red[0][tid] + red[1][tid] + red[2][tid] + red[3][tid];
}

extern "C" void kernel_launch(void* const* d_in, const int* in_sizes, int n_in,
                              void* d_out, int out_size, void* d_ws, size_t ws_size,
                              hipStream_t stream) {
    const float* beta  = (const float*)d_in[0];
    const float* theta = (const float*)d_in[1];
    const float* trans = (const float*)d_in[2];
    const float* sdirs = (const float*)d_in[3];
    const float* vtmpl = (const float*)d_in[4];
    const float* jregJ = (const float*)d_in[5];
    const float* pdirs = (const float*)d_in[6];
    const float* wgts  = (const float*)d_in[7];
    const float* jregK = (const float*)d_in[8];

    float* verts  = (float*)d_out;
    float* joints = verts + (size_t)NBATCH * VC;

    char* ws = (char*)d_ws;
    float*          JB   = (float*)ws;                                   // 3168 B
    unsigned short* Arow = (unsigned short*)(ws + 4096);                 // 2048*224*2
    unsigned short* Gt   = (unsigned short*)(ws + 4096 + 917504);        // 2048*512*2
    unsigned short* Bmat = (unsigned short*)(ws + 4096 + 917504 + 2097152); // 20670*224*2

    k_jb   <<<198, 256, 0, stream>>>(jregJ, vtmpl, sdirs, JB);
    k_bmat <<<(VC*KP + 255)/256, 256, 0, stream>>>(sdirs, pdirs, vtmpl, Bmat);
    k_pern <<<NBATCH, 128, 0, stream>>>(beta, theta, trans, JB, Arow, Gt);
    dim3 g4(NBATCH/BN, (V + BV - 1)/BV);   // (64, 108); x-fastest keeps B tile hot
    k_main <<<g4, 256, 0, stream>>>(Arow, Bmat, Gt, wgts, verts);
    k_joints<<<NBATCH, 256, 0, stream>>>(verts, jregK, joints);
}

// Round 2
// 263.783 us; speedup vs baseline: 2.0200x; 2.0200x over previous
//
#include <hip/hip_runtime.h>

#define V      6890
#define NJ     24
#define NB     10
#define NP     207
#define NK     19
#define NBATCH 2048
#define KP     224      // padded K: 10 beta + 207 lrotmin + 1 const + 6 zero
#define KC     217      // index of the constant-1 column (-> v_template)
#define VC     (V*3)    // 20670
#define VCP    20736    // padded VC (64*108*3) so direct B-fragment reads stay in-bounds

#define BN   32         // n-tile
#define BV   64         // vertex tile
#define VSTR 196        // vh LDS row stride (floats); 196 mod 32 = 4 -> 2-way max (free)

using bh8   = __attribute__((ext_vector_type(8))) short;          // 8 x bf16
using u16x8 = __attribute__((ext_vector_type(8))) unsigned short;
using f32x4 = __attribute__((ext_vector_type(4))) float;

__constant__ int PAR[NJ] = {-1,0,0,0,1,2,3,4,5,6,7,8,9,9,9,12,13,14,16,17,18,19,20,21};

__device__ __forceinline__ unsigned short f2bf(float f) {
    unsigned int u = __float_as_uint(f);
    u += 0x7FFFu + ((u >> 16) & 1u);   // RNE; no NaNs in this data
    return (unsigned short)(u >> 16);
}

// ---------------- K1: JB[j, c, m] = J_regressor . [v_template | shapedirs] ----------------
__global__ __launch_bounds__(256) void k_jb(const float* __restrict__ Jreg,
                                            const float* __restrict__ vtmpl,
                                            const float* __restrict__ sdirs,
                                            float* __restrict__ JB) {
    int o = blockIdx.x * 4 + (threadIdx.x >> 6);
    int lane = threadIdx.x & 63;
    if (o >= NJ * 33) return;
    int j = o / 33, t = o % 33, c = t / 11, m = t % 11;
    const float* jr = Jreg + j * V;
    float s = 0.f;
    if (m == 0) {
        for (int v = lane; v < V; v += 64) s += jr[v] * vtmpl[v*3 + c];
    } else {
        for (int v = lane; v < V; v += 64) s += jr[v] * sdirs[(v*3 + c)*NB + (m-1)];
    }
    #pragma unroll
    for (int d = 1; d < 64; d <<= 1) s += __shfl_xor(s, d);
    if (lane == 0) JB[(j*3 + c)*11 + m] = s;
}

// ---------------- K3: Bmat[vc][k] (bf16) = [shapedirs | posedirs | v_template | 0], rows padded to VCP ----------------
__global__ __launch_bounds__(256) void k_bmat(const float* __restrict__ sdirs,
                                              const float* __restrict__ pdirs,
                                              const float* __restrict__ vtmpl,
                                              unsigned short* __restrict__ Bmat) {
    int gid = blockIdx.x * 256 + threadIdx.x;
    if (gid >= VCP * KP) return;
    int vc = gid / KP, k = gid % KP;
    float val;
    if (vc >= VC)     val = 0.0f;
    else if (k < NB)  val = sdirs[vc*NB + k];
    else if (k < KC)  val = pdirs[vc*NP + (k - NB)];
    else if (k == KC) val = vtmpl[vc];
    else              val = 0.0f;
    Bmat[gid] = f2bf(val);
}

// ---------------- K2: per-n rodrigues, J, kinematic chain, G_rel (+trans), A-row ----------------
__global__ __launch_bounds__(128) void k_pern(const float* __restrict__ beta,
                                              const float* __restrict__ theta,
                                              const float* __restrict__ trans,
                                              const float* __restrict__ JB,
                                              unsigned short* __restrict__ Arow,
                                              unsigned short* __restrict__ Gt) {
    int n = blockIdx.x, tid = threadIdx.x;
    __shared__ float Rsm[NJ][9];
    __shared__ float Jsm[NJ][3];
    __shared__ float Gsm[NJ][12];   // 3x4, e = a*4+b

    if (tid < NJ) {
        const float* th = theta + (n*NJ + tid)*3;
        float x = th[0], y = th[1], z = th[2];
        float nrm = sqrtf(x*x + y*y + z*z);
        float t = fmaxf(nrm, 1.1754944e-38f);
        float inv = 1.0f / t;
        float rx = x*inv, ry = y*inv, rz = z*inv;
        float c = cosf(t), s = sinf(t), oc = 1.0f - c;
        Rsm[tid][0] = c + oc*rx*rx;      Rsm[tid][1] = oc*rx*ry - s*rz;  Rsm[tid][2] = oc*rx*rz + s*ry;
        Rsm[tid][3] = oc*ry*rx + s*rz;   Rsm[tid][4] = c + oc*ry*ry;     Rsm[tid][5] = oc*ry*rz - s*rx;
        Rsm[tid][6] = oc*rz*rx - s*ry;   Rsm[tid][7] = oc*rz*ry + s*rx;  Rsm[tid][8] = c + oc*rz*rz;
    }
    if (tid < NJ*3) {
        int j = tid/3, c = tid%3;
        float s = JB[(j*3+c)*11 + 0];
        #pragma unroll
        for (int b = 0; b < NB; ++b) s += JB[(j*3+c)*11 + 1 + b] * beta[n*NB + b];
        Jsm[j][c] = s;
    }
    __syncthreads();

    if (tid < 12) {   // G[0] = A(R0, J0), top 3 rows
        int a = tid >> 2, b = tid & 3;
        Gsm[0][a*4+b] = (b < 3) ? Rsm[0][a*3+b] : Jsm[0][a];
    }
    __syncthreads();
    for (int i = 1; i < NJ; ++i) {
        if (tid < 12) {
            int a = tid >> 2, b = tid & 3;
            int p = PAR[i];
            float acc = (b == 3) ? Gsm[p][a*4+3] : 0.0f;
            #pragma unroll
            for (int k = 0; k < 3; ++k) {
                float aval = (b < 3) ? Rsm[i][k*3+b] : (Jsm[i][k] - Jsm[p][k]);
                acc += Gsm[p][a*4+k] * aval;
            }
            Gsm[i][a*4+b] = acc;
        }
        __syncthreads();
    }
    // G_rel translation column: t' = t - R_part.J_j + trans  (trans folds since sum_j w = 1)
    if (tid < NJ*3) {
        int j = tid/3, a = tid%3;
        float t3 = Gsm[j][a*4+3]
                 - (Gsm[j][a*4+0]*Jsm[j][0] + Gsm[j][a*4+1]*Jsm[j][1] + Gsm[j][a*4+2]*Jsm[j][2])
                 + trans[n*3 + a];
        Gsm[j][a*4+3] = t3;
    }
    __syncthreads();
    // Gt[n][e=0..15][j=0..31] bf16, zero-padded (MFMA A operand for LBS GEMM)
    unsigned short* gt = Gt + n*512;
    for (int idx = tid; idx < 512; idx += 128) {
        int e = idx >> 5, j = idx & 31;
        float val = (e < 12 && j < NJ) ? Gsm[j][e] : 0.0f;
        gt[idx] = f2bf(val);
    }
    // A-row: [beta(10) | lrotmin(207) | 1 | 0...]
    unsigned short* ar = Arow + n*KP;
    for (int k = tid; k < KP; k += 128) {
        float val;
        if (k < NB) val = beta[n*NB + k];
        else if (k < KC) {
            int p = k - NB; int jj = p/9 + 1; int rr = p%9;
            val = Rsm[jj][rr] - ((rr==0 || rr==4 || rr==8) ? 1.0f : 0.0f);
        } else if (k == KC) val = 1.0f;
        else val = 0.0f;
        ar[k] = f2bf(val);
    }
}

// ---------------- K4: fused pose GEMM (MFMA) + LBS GEMM (MFMA) + apply ----------------
// No A/B LDS staging (all operands L2-resident; staging saved no traffic, only
// added barriers + LDS). Only vh tile lives in LDS. GEMM2 operands SWAPPED
// (T^T = G^T x W) so lane (g,v) holds T[v, a=g, b=0..3] in its 4 accum regs ->
// b-contraction is 3 in-register FMAs, no shuffles.
__global__ __launch_bounds__(256, 4) void k_main(const unsigned short* __restrict__ Arow,
                                                 const unsigned short* __restrict__ Bmat,
                                                 const unsigned short* __restrict__ Gt,
                                                 const float* __restrict__ weights,
                                                 float* __restrict__ verts) {
    __shared__ float vhsm[BN][VSTR];     // 25088 B

    int tid = threadIdx.x;
    int wv = tid >> 6, lane = tid & 63;
    int l15 = lane & 15, jg = lane >> 4;
    int nb = blockIdx.x, vb = blockIdx.y;      // x-fastest => B tile stays hot in L2
    int n0 = nb * BN, v0 = vb * BV, vc0 = v0 * 3;

    // W fragments: B-operand of LBS GEMM, cols=v, k=j (pad j>=24 with 0)
    bh8 wfrag[4];
    #pragma unroll
    for (int mt = 0; mt < 4; ++mt) {
        int vr = v0 + mt*16 + l15;
        bh8 f = {0,0,0,0,0,0,0,0};
        if (jg < 3 && vr < V) {
            const float4* wp = (const float4*)(weights + vr*NJ + jg*8);
            float4 w0 = wp[0], w1 = wp[1];
            f[0]=(short)f2bf(w0.x); f[1]=(short)f2bf(w0.y); f[2]=(short)f2bf(w0.z); f[3]=(short)f2bf(w0.w);
            f[4]=(short)f2bf(w1.x); f[5]=(short)f2bf(w1.y); f[6]=(short)f2bf(w1.z); f[7]=(short)f2bf(w1.w);
        }
        wfrag[mt] = f;
    }

    // GEMM1: vh[n, vc] = Arow . Bmat^T   (K=224, fragments direct from L2, no barriers)
    f32x4 acc[2][3] = {};
    #pragma unroll
    for (int ks = 0; ks < KP/32; ++ks) {
        bh8 af[2], bfr[3];
        #pragma unroll
        for (int mt = 0; mt < 2; ++mt)
            af[mt] = *(const bh8*)(Arow + (size_t)(n0 + mt*16 + l15)*KP + ks*32 + jg*8);
        #pragma unroll
        for (int ct = 0; ct < 3; ++ct)
            bfr[ct] = *(const bh8*)(Bmat + (size_t)(vc0 + wv*48 + ct*16 + l15)*KP + ks*32 + jg*8);
        #pragma unroll
        for (int mt = 0; mt < 2; ++mt)
            #pragma unroll
            for (int ct = 0; ct < 3; ++ct)
                acc[mt][ct] = __builtin_amdgcn_mfma_f32_16x16x32_bf16(af[mt], bfr[ct], acc[mt][ct], 0, 0, 0);
    }
    // spill vh tile to LDS (f32); D layout: col=lane&15, row=(lane>>4)*4+r
    #pragma unroll
    for (int mt = 0; mt < 2; ++mt)
        #pragma unroll
        for (int ct = 0; ct < 3; ++ct)
            #pragma unroll
            for (int r = 0; r < 4; ++r)
                vhsm[mt*16 + jg*4 + r][wv*48 + ct*16 + l15] = acc[mt][ct][r];
    __syncthreads();

    // GEMM2 + apply: T^T[e, v'] = Gt_n . W^T; lane (jg,v') holds T[v', a=jg, b=r].
    // verts[v',a] = t0*x + t1*y + t2*z + t3   (G col3 already has -R.J + trans folded)
    #pragma unroll
    for (int nl = 0; nl < 8; ++nl) {
        int n_loc = wv*8 + nl;
        const bh8 gfrag = *(const bh8*)(Gt + (size_t)(n0 + n_loc)*512 + l15*32 + jg*8);
        #pragma unroll
        for (int mt = 0; mt < 4; ++mt) {
            f32x4 z = {0.f, 0.f, 0.f, 0.f};
            f32x4 t = __builtin_amdgcn_mfma_f32_16x16x32_bf16(gfrag, wfrag[mt], z, 0, 0, 0);
            int vg = v0 + mt*16 + l15;
            if (jg < 3 && vg < V) {
                int vl3 = (mt*16 + l15)*3;
                float x = vhsm[n_loc][vl3+0];
                float y = vhsm[n_loc][vl3+1];
                float zz = vhsm[n_loc][vl3+2];
                verts[(size_t)(n0 + n_loc)*VC + vg*3 + jg] = t[0]*x + t[1]*y + t[2]*zz + t[3];
            }
        }
    }
}

// ---------------- K5: joints[n,k,c] = sum_v verts[n,v,c] * jreg[v,k] ----------------
__global__ __launch_bounds__(256) void k_joints(const float* __restrict__ verts,
                                                const float* __restrict__ jreg,
                                                float* __restrict__ joints) {
    int n = blockIdx.x, tid = threadIdx.x;
    float acc[NK*3];
    #pragma unroll
    for (int i = 0; i < NK*3; ++i) acc[i] = 0.f;
    const float* vr = verts + (size_t)n*VC;
    for (int v = tid; v < V; v += 256) {
        float x = vr[v*3+0], y = vr[v*3+1], z = vr[v*3+2];
        const float* jw = jreg + v*NK;
        #pragma unroll
        for (int k = 0; k < NK; ++k) {
            float w = jw[k];
            acc[k*3+0] += w*x; acc[k*3+1] += w*y; acc[k*3+2] += w*z;
        }
    }
    __shared__ float red[4][NK*3];
    #pragma unroll
    for (int i = 0; i < NK*3; ++i) {
        float s = acc[i];
        #pragma unroll
        for (int d = 1; d < 64; d <<= 1) s += __shfl_xor(s, d);
        if ((tid & 63) == 0) red[tid >> 6][i] = s;
    }
    __syncthreads();
    if (tid < NK*3)
        joints[n*NK*3 + tid] = red[0][tid] + red[1][tid] + red[2][tid] + red[3][tid];
}

extern "C" void kernel_launch(void* const* d_in, const int* in_sizes, int n_in,
                              void* d_out, int out_size, void* d_ws, size_t ws_size,
                              hipStream_t stream) {
    const float* beta  = (const float*)d_in[0];
    const float* theta = (const float*)d_in[1];
    const float* trans = (const float*)d_in[2];
    const float* sdirs = (const float*)d_in[3];
    const float* vtmpl = (const float*)d_in[4];
    const float* jregJ = (const float*)d_in[5];
    const float* pdirs = (const float*)d_in[6];
    const float* wgts  = (const float*)d_in[7];
    const float* jregK = (const float*)d_in[8];

    float* verts  = (float*)d_out;
    float* joints = verts + (size_t)NBATCH * VC;

    char* ws = (char*)d_ws;
    float*          JB   = (float*)ws;                                   // 3168 B
    unsigned short* Arow = (unsigned short*)(ws + 4096);                 // 2048*224*2
    unsigned short* Gt   = (unsigned short*)(ws + 4096 + 917504);        // 2048*512*2
    unsigned short* Bmat = (unsigned short*)(ws + 4096 + 917504 + 2097152); // VCP*224*2

    k_jb   <<<198, 256, 0, stream>>>(jregJ, vtmpl, sdirs, JB);
    k_bmat <<<(VCP*KP + 255)/256, 256, 0, stream>>>(sdirs, pdirs, vtmpl, Bmat);
    k_pern <<<NBATCH, 128, 0, stream>>>(beta, theta, trans, JB, Arow, Gt);
    dim3 g4(NBATCH/BN, (V + BV - 1)/BV);   // (64, 108); x-fastest keeps B tile hot
    k_main <<<g4, 256, 0, stream>>>(Arow, Bmat, Gt, wgts, verts);
    k_joints<<<NBATCH, 256, 0, stream>>>(verts, jregK, joints);
}

// Round 3
// 260.978 us; speedup vs baseline: 2.0417x; 1.0107x over previous
//
#include <hip/hip_runtime.h>

#define V      6890
#define NJ     24
#define NB     10
#define NP     207
#define NK     19
#define NBATCH 2048
#define KP     224      // padded K: 10 beta + 207 lrotmin + 1 const + 6 zero
#define KC     217      // index of the constant-1 column (-> v_template)
#define VC     (V*3)    // 20670
#define VCP    20736    // padded VC (64*108*3) so direct B-fragment reads stay in-bounds

#define BN   32         // n-tile
#define BV   64         // vertex tile
#define VSTR 196        // vhsm row stride (shorts); 2*196%32=8 -> jg rows 8 banks apart (conflict-free)

using bh8   = __attribute__((ext_vector_type(8))) short;          // 8 x bf16
using u16x8 = __attribute__((ext_vector_type(8))) unsigned short;
using f32x4 = __attribute__((ext_vector_type(4))) float;

__constant__ int PAR[NJ] = {-1,0,0,0,1,2,3,4,5,6,7,8,9,9,9,12,13,14,16,17,18,19,20,21};

__device__ __forceinline__ unsigned short f2bf(float f) {
    unsigned int u = __float_as_uint(f);
    u += 0x7FFFu + ((u >> 16) & 1u);   // RNE; no NaNs in this data
    return (unsigned short)(u >> 16);
}
__device__ __forceinline__ float bf2f(unsigned short h) {
    return __uint_as_float((unsigned int)h << 16);
}

// ---------------- K1: JB[j, c, m] = J_regressor . [v_template | shapedirs] ----------------
__global__ __launch_bounds__(256) void k_jb(const float* __restrict__ Jreg,
                                            const float* __restrict__ vtmpl,
                                            const float* __restrict__ sdirs,
                                            float* __restrict__ JB) {
    int o = blockIdx.x * 4 + (threadIdx.x >> 6);
    int lane = threadIdx.x & 63;
    if (o >= NJ * 33) return;
    int j = o / 33, t = o % 33, c = t / 11, m = t % 11;
    const float* jr = Jreg + j * V;
    float s = 0.f;
    if (m == 0) {
        for (int v = lane; v < V; v += 64) s += jr[v] * vtmpl[v*3 + c];
    } else {
        for (int v = lane; v < V; v += 64) s += jr[v] * sdirs[(v*3 + c)*NB + (m-1)];
    }
    #pragma unroll
    for (int d = 1; d < 64; d <<= 1) s += __shfl_xor(s, d);
    if (lane == 0) JB[(j*3 + c)*11 + m] = s;
}

// ---------------- K3: Bmat[vc][k] (bf16) = [shapedirs | posedirs | v_template | 0], rows padded to VCP ----------------
__global__ __launch_bounds__(256) void k_bmat(const float* __restrict__ sdirs,
                                              const float* __restrict__ pdirs,
                                              const float* __restrict__ vtmpl,
                                              unsigned short* __restrict__ Bmat) {
    int gid = blockIdx.x * 256 + threadIdx.x;
    if (gid >= VCP * KP) return;
    int vc = gid / KP, k = gid % KP;
    float val;
    if (vc >= VC)     val = 0.0f;
    else if (k < NB)  val = sdirs[vc*NB + k];
    else if (k < KC)  val = pdirs[vc*NP + (k - NB)];
    else if (k == KC) val = vtmpl[vc];
    else              val = 0.0f;
    Bmat[gid] = f2bf(val);
}

// ---------------- K3b: jregT[k][v] = joint_regressor[v][k] (coalesced consumer layout) ----------------
__global__ __launch_bounds__(256) void k_jt(const float* __restrict__ jreg,
                                            float* __restrict__ jregT) {
    int idx = blockIdx.x * 256 + threadIdx.x;
    if (idx >= NK * V) return;
    int k = idx / V, v = idx - k * V;
    jregT[idx] = jreg[v*NK + k];
}

// ---------------- K2: per-n rodrigues, J, kinematic chain, G_rel (+trans), A-row ----------------
__global__ __launch_bounds__(128) void k_pern(const float* __restrict__ beta,
                                              const float* __restrict__ theta,
                                              const float* __restrict__ trans,
                                              const float* __restrict__ JB,
                                              unsigned short* __restrict__ Arow,
                                              unsigned short* __restrict__ Gt) {
    int n = blockIdx.x, tid = threadIdx.x;
    __shared__ float Rsm[NJ][9];
    __shared__ float Jsm[NJ][3];
    __shared__ float Gsm[NJ][12];   // 3x4, e = a*4+b

    if (tid < NJ) {
        const float* th = theta + (n*NJ + tid)*3;
        float x = th[0], y = th[1], z = th[2];
        float nrm = sqrtf(x*x + y*y + z*z);
        float t = fmaxf(nrm, 1.1754944e-38f);
        float inv = 1.0f / t;
        float rx = x*inv, ry = y*inv, rz = z*inv;
        float c = cosf(t), s = sinf(t), oc = 1.0f - c;
        Rsm[tid][0] = c + oc*rx*rx;      Rsm[tid][1] = oc*rx*ry - s*rz;  Rsm[tid][2] = oc*rx*rz + s*ry;
        Rsm[tid][3] = oc*ry*rx + s*rz;   Rsm[tid][4] = c + oc*ry*ry;     Rsm[tid][5] = oc*ry*rz - s*rx;
        Rsm[tid][6] = oc*rz*rx - s*ry;   Rsm[tid][7] = oc*rz*ry + s*rx;  Rsm[tid][8] = c + oc*rz*rz;
    }
    if (tid < NJ*3) {
        int j = tid/3, c = tid%3;
        float s = JB[(j*3+c)*11 + 0];
        #pragma unroll
        for (int b = 0; b < NB; ++b) s += JB[(j*3+c)*11 + 1 + b] * beta[n*NB + b];
        Jsm[j][c] = s;
    }
    __syncthreads();

    if (tid < 12) {   // G[0] = A(R0, J0), top 3 rows
        int a = tid >> 2, b = tid & 3;
        Gsm[0][a*4+b] = (b < 3) ? Rsm[0][a*3+b] : Jsm[0][a];
    }
    __syncthreads();
    for (int i = 1; i < NJ; ++i) {
        if (tid < 12) {
            int a = tid >> 2, b = tid & 3;
            int p = PAR[i];
            float acc = (b == 3) ? Gsm[p][a*4+3] : 0.0f;
            #pragma unroll
            for (int k = 0; k < 3; ++k) {
                float aval = (b < 3) ? Rsm[i][k*3+b] : (Jsm[i][k] - Jsm[p][k]);
                acc += Gsm[p][a*4+k] * aval;
            }
            Gsm[i][a*4+b] = acc;
        }
        __syncthreads();
    }
    // G_rel translation column: t' = t - R_part.J_j + trans  (trans folds since sum_j w = 1)
    if (tid < NJ*3) {
        int j = tid/3, a = tid%3;
        float t3 = Gsm[j][a*4+3]
                 - (Gsm[j][a*4+0]*Jsm[j][0] + Gsm[j][a*4+1]*Jsm[j][1] + Gsm[j][a*4+2]*Jsm[j][2])
                 + trans[n*3 + a];
        Gsm[j][a*4+3] = t3;
    }
    __syncthreads();
    // Gt[n][e=0..15][j=0..31] bf16, zero-padded (MFMA A operand for LBS GEMM)
    unsigned short* gt = Gt + n*512;
    for (int idx = tid; idx < 512; idx += 128) {
        int e = idx >> 5, j = idx & 31;
        float val = (e < 12 && j < NJ) ? Gsm[j][e] : 0.0f;
        gt[idx] = f2bf(val);
    }
    // A-row: [beta(10) | lrotmin(207) | 1 | 0...]
    unsigned short* ar = Arow + n*KP;
    for (int k = tid; k < KP; k += 128) {
        float val;
        if (k < NB) val = beta[n*NB + k];
        else if (k < KC) {
            int p = k - NB; int jj = p/9 + 1; int rr = p%9;
            val = Rsm[jj][rr] - ((rr==0 || rr==4 || rr==8) ? 1.0f : 0.0f);
        } else if (k == KC) val = 1.0f;
        else val = 0.0f;
        ar[k] = f2bf(val);
    }
}

// ---------------- K4: fused pose GEMM (MFMA) + LBS GEMM (MFMA) + apply ----------------
// Latency-bound fix (R3): hoist all A fragments to registers, double-buffer B and
// G fragments so ~20 L2 loads are in flight per wave; bf16 vhsm halves LDS.
__global__ __launch_bounds__(256, 2) void k_main(const unsigned short* __restrict__ Arow,
                                                 const unsigned short* __restrict__ Bmat,
                                                 const unsigned short* __restrict__ Gt,
                                                 const float* __restrict__ weights,
                                                 float* __restrict__ verts) {
    __shared__ unsigned short vhsm[BN][VSTR];     // 12544 B, bf16

    int tid = threadIdx.x;
    int wv = tid >> 6, lane = tid & 63;
    int l15 = lane & 15, jg = lane >> 4;
    int nb = blockIdx.x, vb = blockIdx.y;      // x-fastest => B tile stays hot in L2
    int n0 = nb * BN, v0 = vb * BV, vc0 = v0 * 3;

    // Hoist ALL A fragments (14 x dwordx4) - issued up front, in flight together
    bh8 afall[7][2];
    const unsigned short* arow0 = Arow + (size_t)(n0 + l15)*KP + jg*8;
    #pragma unroll
    for (int ks = 0; ks < 7; ++ks)
        #pragma unroll
        for (int mt = 0; mt < 2; ++mt)
            afall[ks][mt] = *(const bh8*)(arow0 + mt*16*KP + ks*32);

    // W fragments: B-operand of LBS GEMM, cols=v, k=j (pad j>=24 with 0)
    bh8 wfrag[4];
    #pragma unroll
    for (int mt = 0; mt < 4; ++mt) {
        int vr = v0 + mt*16 + l15;
        bh8 f = {0,0,0,0,0,0,0,0};
        if (jg < 3 && vr < V) {
            const float4* wp = (const float4*)(weights + vr*NJ + jg*8);
            float4 w0 = wp[0], w1 = wp[1];
            f[0]=(short)f2bf(w0.x); f[1]=(short)f2bf(w0.y); f[2]=(short)f2bf(w0.z); f[3]=(short)f2bf(w0.w);
            f[4]=(short)f2bf(w1.x); f[5]=(short)f2bf(w1.y); f[6]=(short)f2bf(w1.z); f[7]=(short)f2bf(w1.w);
        }
        wfrag[mt] = f;
    }

    // GEMM1: vh[n, vc] = Arow . Bmat^T   (K=224, B fragments double-buffered from L2)
    const unsigned short* bbase0 = Bmat + (size_t)(vc0 + wv*48 + l15)*KP + jg*8;
    f32x4 acc[2][3] = {};
    bh8 bcur[3], bnxt[3];
    #pragma unroll
    for (int ct = 0; ct < 3; ++ct)
        bcur[ct] = *(const bh8*)(bbase0 + (size_t)ct*16*KP);
    #pragma unroll
    for (int ks = 0; ks < 7; ++ks) {
        if (ks < 6) {
            #pragma unroll
            for (int ct = 0; ct < 3; ++ct)
                bnxt[ct] = *(const bh8*)(bbase0 + (size_t)ct*16*KP + (ks+1)*32);
        }
        #pragma unroll
        for (int mt = 0; mt < 2; ++mt)
            #pragma unroll
            for (int ct = 0; ct < 3; ++ct)
                acc[mt][ct] = __builtin_amdgcn_mfma_f32_16x16x32_bf16(afall[ks][mt], bcur[ct], acc[mt][ct], 0, 0, 0);
        if (ks < 6) {
            #pragma unroll
            for (int ct = 0; ct < 3; ++ct) bcur[ct] = bnxt[ct];
        }
    }
    // spill vh tile to LDS (bf16); D layout: col=lane&15, row=(lane>>4)*4+r
    #pragma unroll
    for (int mt = 0; mt < 2; ++mt)
        #pragma unroll
        for (int ct = 0; ct < 3; ++ct)
            #pragma unroll
            for (int r = 0; r < 4; ++r)
                vhsm[mt*16 + jg*4 + r][wv*48 + ct*16 + l15] = f2bf(acc[mt][ct][r]);
    __syncthreads();

    // GEMM2 + apply: T^T[e, v'] = Gt_n . W^T; lane (jg,v') holds T[v', a=jg, b=r].
    // verts[v',a] = t0*x + t1*y + t2*z + t3   (G col3 already has -R.J + trans folded)
    const unsigned short* gbase = Gt + (size_t)(n0 + wv*8)*512 + l15*32 + jg*8;
    bh8 gcur = *(const bh8*)gbase;
    #pragma unroll
    for (int nl = 0; nl < 8; ++nl) {
        int n_loc = wv*8 + nl;
        bh8 gnxt = gcur;
        if (nl < 7) gnxt = *(const bh8*)(gbase + (nl+1)*512);
        #pragma unroll
        for (int mt = 0; mt < 4; ++mt) {
            f32x4 z = {0.f, 0.f, 0.f, 0.f};
            f32x4 t = __builtin_amdgcn_mfma_f32_16x16x32_bf16(gcur, wfrag[mt], z, 0, 0, 0);
            int vl = mt*16 + l15;
            int vg = v0 + vl;
            if (jg < 3 && vg < V) {
                float x  = bf2f(vhsm[n_loc][vl*3+0]);
                float y  = bf2f(vhsm[n_loc][vl*3+1]);
                float zz = bf2f(vhsm[n_loc][vl*3+2]);
                verts[(size_t)(n0 + n_loc)*VC + (size_t)vg*3 + jg] = t[0]*x + t[1]*y + t[2]*zz + t[3];
            }
        }
        gcur = gnxt;
    }
}

// ---------------- K5: joints[n,k,c] = sum_v verts[n,v,c] * jregT[k,v] (coalesced) ----------------
__global__ __launch_bounds__(256) void k_joints(const float* __restrict__ verts,
                                                const float* __restrict__ jregT,
                                                float* __restrict__ joints) {
    int n = blockIdx.x, tid = threadIdx.x;
    float acc[NK*3];
    #pragma unroll
    for (int i = 0; i < NK*3; ++i) acc[i] = 0.f;
    const float* vr = verts + (size_t)n*VC;
    for (int v = tid; v < V; v += 256) {
        float x = vr[v*3+0], y = vr[v*3+1], z = vr[v*3+2];
        #pragma unroll
        for (int k = 0; k < NK; ++k) {
            float w = jregT[k*V + v];
            acc[k*3+0] += w*x; acc[k*3+1] += w*y; acc[k*3+2] += w*z;
        }
    }
    __shared__ float red[4][NK*3];
    #pragma unroll
    for (int i = 0; i < NK*3; ++i) {
        float s = acc[i];
        #pragma unroll
        for (int d = 1; d < 64; d <<= 1) s += __shfl_xor(s, d);
        if ((tid & 63) == 0) red[tid >> 6][i] = s;
    }
    __syncthreads();
    if (tid < NK*3)
        joints[n*NK*3 + tid] = red[0][tid] + red[1][tid] + red[2][tid] + red[3][tid];
}

extern "C" void kernel_launch(void* const* d_in, const int* in_sizes, int n_in,
                              void* d_out, int out_size, void* d_ws, size_t ws_size,
                              hipStream_t stream) {
    const float* beta  = (const float*)d_in[0];
    const float* theta = (const float*)d_in[1];
    const float* trans = (const float*)d_in[2];
    const float* sdirs = (const float*)d_in[3];
    const float* vtmpl = (const float*)d_in[4];
    const float* jregJ = (const float*)d_in[5];
    const float* pdirs = (const float*)d_in[6];
    const float* wgts  = (const float*)d_in[7];
    const float* jregK = (const float*)d_in[8];

    float* verts  = (float*)d_out;
    float* joints = verts + (size_t)NBATCH * VC;

    char* ws = (char*)d_ws;
    float*          JB    = (float*)ws;                                      // 3168 B
    unsigned short* Arow  = (unsigned short*)(ws + 4096);                    // 2048*224*2
    unsigned short* Gt    = (unsigned short*)(ws + 4096 + 917504);           // 2048*512*2
    unsigned short* Bmat  = (unsigned short*)(ws + 4096 + 917504 + 2097152); // VCP*224*2 = 9289728
    float*          jregT = (float*)(ws + 4096 + 917504 + 2097152 + 9289728);// 19*6890*4

    k_jb   <<<198, 256, 0, stream>>>(jregJ, vtmpl, sdirs, JB);
    k_bmat <<<(VCP*KP + 255)/256, 256, 0, stream>>>(sdirs, pdirs, vtmpl, Bmat);
    k_jt   <<<(NK*V + 255)/256, 256, 0, stream>>>(jregK, jregT);
    k_pern <<<NBATCH, 128, 0, stream>>>(beta, theta, trans, JB, Arow, Gt);
    dim3 g4(NBATCH/BN, (V + BV - 1)/BV);   // (64, 108); x-fastest keeps B tile hot
    k_main <<<g4, 256, 0, stream>>>(Arow, Bmat, Gt, wgts, verts);
    k_joints<<<NBATCH, 256, 0, stream>>>(verts, jregT, joints);
}